// Round 14
// baseline (103.277 us; speedup 1.0000x reference)
//
#include <hip/hip_runtime.h>
#include <cstdint>
#include <cstddef>

// ---------------------------------------------------------------------------
// MultiHeadExternalAttention, algebraically collapsed:
//   logits = x @ Wk + bk ; attn = softmax_n -> L1_m ; out = attn @ Wv + bv
// B=32 N=1024 E=512 H=16 M=16 HM=256 ROWS=32768
// Round 14: gemm_b rebuilt BARRIER-FREE / wave-independent (fill-like):
//   wave owns 16 rows; softmax in-register (once; head-sum = 1 shfl_xor);
//   P persists in 32 VGPR across both col-halves; B per-lane from L2-hot
//   wvTf; stores via per-wave-private LDS region (no __syncthreads at all).
// gemm_a + preps unchanged from round 13 (single-variable attribution).
// ---------------------------------------------------------------------------

typedef unsigned short u16;
typedef unsigned int u32;
typedef short s16x8 __attribute__((ext_vector_type(8)));
typedef float f32x4 __attribute__((ext_vector_type(4)));

// workspace layout (bytes)
constexpr size_t OFF_WKT  = 1u << 20;                 // u16 [64][256][8] (256 KiB)
constexpr size_t OFF_WVT  = OFF_WKT + (1u << 18);     // u16 [32][512][8] (256 KiB)
constexpr size_t OFF_BK   = OFF_WVT + (1u << 18);     // f32 [256]
constexpr size_t OFF_BV   = OFF_BK + 4096;            // f32 [512]
constexpr size_t OFF_INV  = OFF_BV + 4096;            // f32 [32][256]
constexpr size_t OFF_CP   = 2u << 20;                 // f32 [512][256]
constexpr size_t OFF_LOG  = 4u << 20;                 // u16 [32768][256] (16 MiB)
constexpr size_t OFF_WVP  = 40u << 20;                // f32 partials (4 MiB)
constexpr size_t OFF_BVP  = 45u << 20;                // f32 partials (256 KiB)

__device__ __forceinline__ float bf2f(u16 v) {
  union { u32 u; float f; } c; c.u = ((u32)v) << 16; return c.f;
}
__device__ __forceinline__ u16 f2bf(float f) {
  union { float f; u32 u; } c; c.f = f;
  u32 u = c.u;
  u += 0x7fffu + ((u >> 16) & 1u);
  return (u16)(u >> 16);
}
__device__ __forceinline__ u32 cvt2(float lo, float hi) {
  u32 r;
  asm("v_cvt_pk_bf16_f32 %0, %1, %2" : "=v"(r) : "v"(lo), "v"(hi));
  return r;
}
__device__ __forceinline__ uint4 pack_bf8(float4 lo, float4 hi) {
  return make_uint4(cvt2(lo.x, lo.y), cvt2(lo.z, lo.w),
                    cvt2(hi.x, hi.y), cvt2(hi.z, hi.w));
}
__device__ __forceinline__ s16x8 as_s16x8(uint4 v) {
  union { uint4 u; s16x8 s; } c; c.u = v; return c.s;
}
__device__ __forceinline__ void mfma_bf16(f32x4& acc, s16x8 a, s16x8 b) {
  asm volatile("v_mfma_f32_16x16x32_bf16 %0, %1, %2, %0"
               : "+v"(acc) : "v"(a), "v"(b));
}
__device__ __forceinline__ void gl16(const void* g, void* l) {
  __builtin_amdgcn_global_load_lds(
      (const __attribute__((address_space(1))) void*)g,
      (__attribute__((address_space(3))) void*)l, 16, 0, 0);
}

// ---------------------------------------------------------------------------
// wkT_f[kg = e>>3][hm][idx = e&7] = sum_d W_in[e, h*128+d] * W_mk[d, m]
__global__ void prep_wkt(const float* __restrict__ wi, const float* __restrict__ wm,
                         u16* __restrict__ wkTf) {
  const int gid = blockIdx.x * 256 + threadIdx.x;
  const int hm = gid & 255, e = gid >> 8;
  const int h = hm >> 4, m = hm & 15;
  float acc = 0.f;
  for (int d = 0; d < 128; d++)
    acc += wi[e * 2048 + h * 128 + d] * wm[d * 16 + m];
  wkTf[((((size_t)(e >> 3)) * 256 + hm) << 3) + (e & 7)] = f2bf(acc);
}

// wvt partial: block = (h, dc); 16 d's per chunk; coalesced W_out rows.
__global__ __launch_bounds__(256) void wvt_part(const float* __restrict__ mv,
                                                const float* __restrict__ b_mv,
                                                const float* __restrict__ wo,
                                                float* __restrict__ wvp,
                                                float* __restrict__ bvp) {
  __shared__ float wmv_l[16][16];
  __shared__ float bmv_l[16];
  const int blk = blockIdx.x;
  const int h = blk >> 3, dc = blk & 7;
  const int t = threadIdx.x;
  {
    const int m = t >> 4, dd = t & 15;
    wmv_l[m][dd] = mv[m * 128 + dc * 16 + dd];
    if (t < 16) bmv_l[t] = b_mv[dc * 16 + t];
  }
  __syncthreads();
  float acc0[16], acc1[16];
  float bv0 = 0.f, bv1 = 0.f;
#pragma unroll
  for (int m = 0; m < 16; m++) { acc0[m] = 0.f; acc1[m] = 0.f; }
#pragma unroll
  for (int dd = 0; dd < 16; dd++) {
    const float w0 = wo[(size_t)(h * 128 + dc * 16 + dd) * 512 + t];
    const float w1 = wo[(size_t)(h * 128 + dc * 16 + dd) * 512 + 256 + t];
#pragma unroll
    for (int m = 0; m < 16; m++) {
      const float c = wmv_l[m][dd];
      acc0[m] += c * w0;
      acc1[m] += c * w1;
    }
    bv0 += bmv_l[dd] * w0;
    bv1 += bmv_l[dd] * w1;
  }
  float* w0p = wvp + ((size_t)blk * 512 + t) * 16;
  float* w1p = wvp + ((size_t)blk * 512 + 256 + t) * 16;
#pragma unroll
  for (int m = 0; m < 16; m++) { w0p[m] = acc0[m]; w1p[m] = acc1[m]; }
  bvp[(size_t)blk * 512 + t] = bv0;
  bvp[(size_t)blk * 512 + 256 + t] = bv1;
}

// wvT_f[kg = hm>>3][e][idx = hm&7] = f2bf(sum_dc wvp); bv = b_out + sum bvp
__global__ __launch_bounds__(256) void wvt_fin(const float* __restrict__ wvp,
                                               const float* __restrict__ bvp,
                                               const float* __restrict__ b_out,
                                               u16* __restrict__ wvTf,
                                               float* __restrict__ bv) {
  const int e = blockIdx.x;   // 512
  const int t = threadIdx.x;  // 256 = hm
  const int h = t >> 4, m = t & 15;
  float s = 0.f;
#pragma unroll
  for (int dc = 0; dc < 8; dc++)
    s += wvp[((size_t)(h * 8 + dc) * 512 + e) * 16 + m];
  wvTf[((((size_t)(t >> 3)) * 512 + e) << 3) + (t & 7)] = f2bf(s);
  if (t < 64) {
    float b = bvp[(size_t)t * 512 + e] + bvp[(size_t)(t + 64) * 512 + e];
#pragma unroll
    for (int mask = 32; mask >= 1; mask >>= 1) b += __shfl_xor(b, mask);
    if (t == 0) bv[e] = b_out[e] + b;
  }
}

// bk[hm] = b_mk[m] + sum_d b_in[h*128+d]*W_mk[d,m]
__global__ void prep_bk(const float* __restrict__ b_in, const float* __restrict__ wm,
                        const float* __restrict__ b_mk, float* __restrict__ bk) {
  const int t = threadIdx.x;
  const int h = t >> 4, m = t & 15;
  float acc = b_mk[m];
  for (int d = 0; d < 128; d++) acc += b_in[h * 128 + d] * wm[d * 16 + m];
  bk[t] = acc;
}

// ---------------------------------------------------------------------------
// GEMM A (round-13 structure, unchanged): BK=64 A-dbuf via global_load_lds,
// B per-lane frags from wkTf, fused colsum.
__global__ __launch_bounds__(256, 4) void gemm_a(const float* __restrict__ x,
                                                 const u16* __restrict__ wkTf,
                                                 const float* __restrict__ bk,
                                                 u16* __restrict__ logits,
                                                 float* __restrict__ cpart) {
  __shared__ float Asf[2][4096];  // 2 x 16 KB: 64 rows x 256 B (swizzled)
  __shared__ float cs[2][128];
  const int t = threadIdx.x;
  const int l = t & 63, w = t >> 6;
  const int wr = w >> 1, wc = w & 1;
  const int lrow = l & 15, lkg = l >> 4;
  const int gCol0 = blockIdx.x << 7;
  const int gRow0 = blockIdx.y << 6;

  const char* xb = (const char*)x;
  const char* gA[4]; int lAo[4];
#pragma unroll
  for (int p = 0; p < 4; p++) {
    const int o = p * 4096 + t * 16;              // phys byte 0..16383
    const int row = o >> 8, pin = o & 255;
    const int lin = pin ^ ((row & 7) << 5);       // logical byte in 256B row
    gA[p] = xb + (size_t)(gRow0 + row) * 2048 + lin;
    lAo[p] = o;
  }
  const int col0 = gCol0 + wc * 64 + lrow;        // + n*16

  f32x4 acc[2][4];
#pragma unroll
  for (int i = 0; i < 2; i++)
#pragma unroll
    for (int n = 0; n < 4; n++) acc[i][n] = f32x4{0.f, 0.f, 0.f, 0.f};

  uint4 bReg[2][4];
#pragma unroll
  for (int p = 0; p < 4; p++) gl16(gA[p], (char*)(&Asf[0][0]) + lAo[p]);
#pragma unroll
  for (int n = 0; n < 4; n++)
    bReg[0][n] = *(const uint4*)(wkTf + ((size_t)lkg * 256 + col0 + n * 16) * 8);
  __syncthreads();

  for (int kc = 0; kc < 8; ++kc) {
    const int buf = kc & 1;
    if (kc < 7) {
#pragma unroll
      for (int p = 0; p < 4; p++)
        gl16(gA[p] + (size_t)(kc + 1) * 256, (char*)(&Asf[buf ^ 1][0]) + lAo[p]);
    }
#pragma unroll
    for (int s = 0; s < 2; ++s) {
      const int nkc = (s == 0) ? kc : kc + 1;
      const int nss = s ^ 1;
      if (nkc < 8) {
#pragma unroll
        for (int n = 0; n < 4; n++)
          bReg[s ^ 1][n] = *(const uint4*)(
              wkTf + ((size_t)(nkc * 8 + nss * 4 + lkg) * 256 + col0 + n * 16) * 8);
      }
      s16x8 af[2];
#pragma unroll
      for (int i = 0; i < 2; i++) {
        const int r = wr * 32 + i * 16 + lrow;
        const int phys = (s * 128 + lkg * 32) ^ ((r & 7) << 5);
        const float4 a0 = *(const float4*)&Asf[buf][r * 64 + (phys >> 2)];
        const float4 a1 = *(const float4*)&Asf[buf][r * 64 + (phys >> 2) + 4];
        af[i] = as_s16x8(pack_bf8(a0, a1));
      }
#pragma unroll
      for (int n = 0; n < 4; n++) {
        const s16x8 bfr = as_s16x8(bReg[s][n]);
#pragma unroll
        for (int i = 0; i < 2; i++) mfma_bf16(acc[i][n], af[i], bfr);
      }
    }
    __syncthreads();
  }

  asm volatile("s_nop 7\n\ts_nop 7");
  const int crow = lkg * 4;
  float esum[4];
#pragma unroll
  for (int n = 0; n < 4; n++) {
    const int col = gCol0 + wc * 64 + n * 16 + lrow;
    const float bias = bk[col];
    float es = 0.f;
#pragma unroll
    for (int i = 0; i < 2; i++) {
      const int row0 = gRow0 + wr * 32 + i * 16 + crow;
#pragma unroll
      for (int j = 0; j < 4; j++) {
        const u16 q = f2bf(acc[i][n][j] + bias);
        logits[(size_t)(row0 + j) * 256 + col] = q;
        es += __expf(bf2f(q));
      }
    }
    esum[n] = es;
  }
#pragma unroll
  for (int n = 0; n < 4; n++) {
    esum[n] += __shfl_xor(esum[n], 16);
    esum[n] += __shfl_xor(esum[n], 32);
  }
  if (l < 16) {
#pragma unroll
    for (int n = 0; n < 4; n++) cs[wr][wc * 64 + n * 16 + l] = esum[n];
  }
  __syncthreads();
  if (t < 128)
    cpart[(size_t)blockIdx.y * 256 + gCol0 + t] = cs[0][t] + cs[1][t];
}

// inv[b][hm] = 1 / sum over the batch's 16 row-block partials
__global__ void colsum_fin(const float* __restrict__ cpart, float* __restrict__ inv) {
  const int b = blockIdx.x, hm = threadIdx.x;
  float s = 0.f;
#pragma unroll
  for (int k = 0; k < 16; k++) s += cpart[(size_t)(b * 16 + k) * 256 + hm];
  inv[b * 256 + hm] = 1.0f / s;
}

// ---------------------------------------------------------------------------
// GEMM B (barrier-free, wave-independent): out = P @ Wv + bv (fp32).
// Grid 512 blocks x 256 thr (4 waves); wave owns 16 rows end-to-end.
// Phase A (in-register, once): lane reads its 8 A-frag granules of lg
//   (lrow = row, lkg = kg class), exp*inv, head-sum = Σ8 + shfl_xor(16),
//   pack -> af[8] (32 VGPR). P never touches LDS.
// Phase B per col-half (256 cols): 16 independent acc chains; B frags
//   per-lane from L2-hot frag-contiguous wvTf, depth-1 prefetch; store
//   via per-wave-PRIVATE 16KB LDS region (intra-wave lgkmcnt only) as
//   float4 (4 x 256B segments / instr). ZERO __syncthreads.
__global__ __launch_bounds__(256, 2) void gemm_b(const u16* __restrict__ lg,
                                                 const float* __restrict__ inv,
                                                 const u16* __restrict__ wvTf,
                                                 const float* __restrict__ bvv,
                                                 float* __restrict__ out) {
  __shared__ float Ob[4][16][256];  // 64 KiB: per-wave private bounce
  const int t = threadIdx.x;
  const int l = t & 63, w = t >> 6;
  const int lrow = l & 15, lkg = l >> 4;
  const int gRow0 = blockIdx.x << 6;
  const int bIdx = blockIdx.x >> 4;
  const int rowBase = gRow0 + w * 16;

  // ---- phase A: softmax -> af[8] in registers ----
  const u16* aBase = lg + (size_t)(rowBase + lrow) * 256 + lkg * 8;
  const float* ivB = inv + bIdx * 256 + lkg * 8;
  s16x8 af[8];
#pragma unroll
  for (int kc = 0; kc < 8; ++kc) {
    const uint4 q = *(const uint4*)(aBase + kc * 32);
    const float4 i0 = *(const float4*)(ivB + kc * 32);
    const float4 i1 = *(const float4*)(ivB + kc * 32 + 4);
    const float e0 = __expf(bf2f((u16)(q.x & 0xffffu))) * i0.x;
    const float e1 = __expf(bf2f((u16)(q.x >> 16)))     * i0.y;
    const float e2 = __expf(bf2f((u16)(q.y & 0xffffu))) * i0.z;
    const float e3 = __expf(bf2f((u16)(q.y >> 16)))     * i0.w;
    const float e4 = __expf(bf2f((u16)(q.z & 0xffffu))) * i1.x;
    const float e5 = __expf(bf2f((u16)(q.z >> 16)))     * i1.y;
    const float e6 = __expf(bf2f((u16)(q.w & 0xffffu))) * i1.z;
    const float e7 = __expf(bf2f((u16)(q.w >> 16)))     * i1.w;
    float s = ((e0 + e1) + (e2 + e3)) + ((e4 + e5) + (e6 + e7));
    s += __shfl_xor(s, 16);  // lkg 0<->1 (head 2kc), 2<->3 (head 2kc+1)
    const float rs = 1.0f / (s + 1e-9f);
    af[kc] = as_s16x8(make_uint4(cvt2(e0 * rs, e1 * rs), cvt2(e2 * rs, e3 * rs),
                                 cvt2(e4 * rs, e5 * rs), cvt2(e6 * rs, e7 * rs)));
  }

  // ---- phase B: two 256-col halves, P reused from registers ----
#pragma unroll
  for (int ch = 0; ch < 2; ++ch) {
    f32x4 acc[16];
#pragma unroll
    for (int n = 0; n < 16; n++) acc[n] = f32x4{0.f, 0.f, 0.f, 0.f};

    const int colB = ch * 256 + lrow;  // + n*16
#pragma unroll
    for (int kc = 0; kc < 8; ++kc) {
      const u16* bb = wvTf + ((size_t)(kc * 4 + lkg) * 512 + colB) * 8;
      uint4 cur = *(const uint4*)(bb);
#pragma unroll
      for (int n = 0; n < 16; ++n) {
        uint4 nxt;
        if (n < 15) nxt = *(const uint4*)(bb + (size_t)(n + 1) * 128);
        mfma_bf16(acc[n], af[kc], as_s16x8(cur));
        if (n < 15) cur = nxt;
      }
    }

    // per-wave LDS bounce (no barrier: region private to this wave)
#pragma unroll
    for (int n = 0; n < 16; ++n) {
      const float bias = bvv[ch * 256 + n * 16 + lrow];
#pragma unroll
      for (int j = 0; j < 4; ++j)
        Ob[w][lkg * 4 + j][n * 16 + lrow] = acc[n][j] + bias;
    }
    // readback + contiguous stores (compiler inserts lgkmcnt for same-wave RAW)
#pragma unroll
    for (int ii = 0; ii < 16; ++ii) {
      const int rr = (ii & 3) * 4 + lkg;
      const int cc = (ii >> 2) * 64 + lrow * 4;
      const float4 v = *(const float4*)&Ob[w][rr][cc];
      *(float4*)(out + (size_t)(rowBase + rr) * 512 + ch * 256 + cc) = v;
    }
  }
}

// ---------------------------------------------------------------------------
extern "C" void kernel_launch(void* const* d_in, const int* in_sizes, int n_in,
                              void* d_out, int out_size, void* d_ws, size_t ws_size,
                              hipStream_t stream) {
  (void)in_sizes; (void)n_in; (void)out_size; (void)ws_size;
  const float* x     = (const float*)d_in[0];
  const float* W_in  = (const float*)d_in[1];
  const float* b_in  = (const float*)d_in[2];
  const float* W_mk  = (const float*)d_in[3];
  const float* b_mk  = (const float*)d_in[4];
  const float* W_mv  = (const float*)d_in[5];
  const float* b_mv  = (const float*)d_in[6];
  const float* W_out = (const float*)d_in[7];
  const float* b_out = (const float*)d_in[8];

  char* ws = (char*)d_ws;
  u16*   wkTf = (u16*)(ws + OFF_WKT);
  u16*   wvTf = (u16*)(ws + OFF_WVT);
  float* bk   = (float*)(ws + OFF_BK);
  float* bv   = (float*)(ws + OFF_BV);
  float* inv  = (float*)(ws + OFF_INV);
  float* cp   = (float*)(ws + OFF_CP);
  u16*   lg   = (u16*)(ws + OFF_LOG);
  float* wvp  = (float*)(ws + OFF_WVP);
  float* bvp  = (float*)(ws + OFF_BVP);
  float* outp = (float*)d_out;

  prep_wkt<<<512, 256, 0, stream>>>(W_in, W_mk, wkTf);
  wvt_part<<<128, 256, 0, stream>>>(W_mv, b_mv, W_out, wvp, bvp);
  wvt_fin<<<512, 256, 0, stream>>>(wvp, bvp, b_out, wvTf, bv);
  prep_bk<<<1, 256, 0, stream>>>(b_in, W_mk, b_mk, bk);
  gemm_a<<<dim3(2, 512), 256, 0, stream>>>(x, wkTf, bk, lg, cp);
  colsum_fin<<<32, 256, 0, stream>>>(cp, inv);
  gemm_b<<<512, 256, 0, stream>>>(lg, inv, wvTf, bv, outp);
}

// Round 15
// 75.617 us; speedup vs baseline: 1.3658x; 1.3658x over previous
//
#include <hip/hip_runtime.h>
#include <cstdint>
#include <cstddef>

// ---------------------------------------------------------------------------
// MultiHeadExternalAttention, algebraically collapsed:
//   logits = x @ Wk + bk ; attn = softmax_n -> L1_m ; out = attn @ Wv + bv
// B=32 N=1024 E=512 H=16 M=16 HM=256 ROWS=32768
// Round 15: gemm_b = hybrid of proven halves. Block = 128 rows x ALL 512
// cols (grid 256, 8 waves): lg read ONCE; per-wave IN-REGISTER softmax
// (r14-verified phase A); B SHARED per block via LDS, staged per 128-col
// quarter with coalesced global_load_lds from frag-contiguous wvTf
// (64 MB total B traffic vs r14's 512 MB). [kg][col] cells = measured-0-
// conflict layout (r8). gemm_a + preps unchanged from r13.
// ---------------------------------------------------------------------------

typedef unsigned short u16;
typedef unsigned int u32;
typedef short s16x8 __attribute__((ext_vector_type(8)));
typedef float f32x4 __attribute__((ext_vector_type(4)));

// workspace layout (bytes)
constexpr size_t OFF_WKT  = 1u << 20;                 // u16 [64][256][8] (256 KiB)
constexpr size_t OFF_WVT  = OFF_WKT + (1u << 18);     // u16 [32][512][8] (256 KiB)
constexpr size_t OFF_BK   = OFF_WVT + (1u << 18);     // f32 [256]
constexpr size_t OFF_BV   = OFF_BK + 4096;            // f32 [512]
constexpr size_t OFF_INV  = OFF_BV + 4096;            // f32 [32][256]
constexpr size_t OFF_CP   = 2u << 20;                 // f32 [512][256]
constexpr size_t OFF_LOG  = 4u << 20;                 // u16 [32768][256] (16 MiB)
constexpr size_t OFF_WVP  = 40u << 20;                // f32 partials (4 MiB)
constexpr size_t OFF_BVP  = 45u << 20;                // f32 partials (256 KiB)

__device__ __forceinline__ float bf2f(u16 v) {
  union { u32 u; float f; } c; c.u = ((u32)v) << 16; return c.f;
}
__device__ __forceinline__ u16 f2bf(float f) {
  union { float f; u32 u; } c; c.f = f;
  u32 u = c.u;
  u += 0x7fffu + ((u >> 16) & 1u);
  return (u16)(u >> 16);
}
__device__ __forceinline__ u32 cvt2(float lo, float hi) {
  u32 r;
  asm("v_cvt_pk_bf16_f32 %0, %1, %2" : "=v"(r) : "v"(lo), "v"(hi));
  return r;
}
__device__ __forceinline__ uint4 pack_bf8(float4 lo, float4 hi) {
  return make_uint4(cvt2(lo.x, lo.y), cvt2(lo.z, lo.w),
                    cvt2(hi.x, hi.y), cvt2(hi.z, hi.w));
}
__device__ __forceinline__ s16x8 as_s16x8(uint4 v) {
  union { uint4 u; s16x8 s; } c; c.u = v; return c.s;
}
__device__ __forceinline__ void mfma_bf16(f32x4& acc, s16x8 a, s16x8 b) {
  asm volatile("v_mfma_f32_16x16x32_bf16 %0, %1, %2, %0"
               : "+v"(acc) : "v"(a), "v"(b));
}
__device__ __forceinline__ void gl16(const void* g, void* l) {
  __builtin_amdgcn_global_load_lds(
      (const __attribute__((address_space(1))) void*)g,
      (__attribute__((address_space(3))) void*)l, 16, 0, 0);
}

// ---------------------------------------------------------------------------
// wkT_f[kg = e>>3][hm][idx = e&7] = sum_d W_in[e, h*128+d] * W_mk[d, m]
__global__ void prep_wkt(const float* __restrict__ wi, const float* __restrict__ wm,
                         u16* __restrict__ wkTf) {
  const int gid = blockIdx.x * 256 + threadIdx.x;
  const int hm = gid & 255, e = gid >> 8;
  const int h = hm >> 4, m = hm & 15;
  float acc = 0.f;
  for (int d = 0; d < 128; d++)
    acc += wi[e * 2048 + h * 128 + d] * wm[d * 16 + m];
  wkTf[((((size_t)(e >> 3)) * 256 + hm) << 3) + (e & 7)] = f2bf(acc);
}

// wvt partial: block = (h, dc); 16 d's per chunk; coalesced W_out rows.
__global__ __launch_bounds__(256) void wvt_part(const float* __restrict__ mv,
                                                const float* __restrict__ b_mv,
                                                const float* __restrict__ wo,
                                                float* __restrict__ wvp,
                                                float* __restrict__ bvp) {
  __shared__ float wmv_l[16][16];
  __shared__ float bmv_l[16];
  const int blk = blockIdx.x;
  const int h = blk >> 3, dc = blk & 7;
  const int t = threadIdx.x;
  {
    const int m = t >> 4, dd = t & 15;
    wmv_l[m][dd] = mv[m * 128 + dc * 16 + dd];
    if (t < 16) bmv_l[t] = b_mv[dc * 16 + t];
  }
  __syncthreads();
  float acc0[16], acc1[16];
  float bv0 = 0.f, bv1 = 0.f;
#pragma unroll
  for (int m = 0; m < 16; m++) { acc0[m] = 0.f; acc1[m] = 0.f; }
#pragma unroll
  for (int dd = 0; dd < 16; dd++) {
    const float w0 = wo[(size_t)(h * 128 + dc * 16 + dd) * 512 + t];
    const float w1 = wo[(size_t)(h * 128 + dc * 16 + dd) * 512 + 256 + t];
#pragma unroll
    for (int m = 0; m < 16; m++) {
      const float c = wmv_l[m][dd];
      acc0[m] += c * w0;
      acc1[m] += c * w1;
    }
    bv0 += bmv_l[dd] * w0;
    bv1 += bmv_l[dd] * w1;
  }
  float* w0p = wvp + ((size_t)blk * 512 + t) * 16;
  float* w1p = wvp + ((size_t)blk * 512 + 256 + t) * 16;
#pragma unroll
  for (int m = 0; m < 16; m++) { w0p[m] = acc0[m]; w1p[m] = acc1[m]; }
  bvp[(size_t)blk * 512 + t] = bv0;
  bvp[(size_t)blk * 512 + 256 + t] = bv1;
}

// wvT_f[kg = hm>>3][e][idx = hm&7] = f2bf(sum_dc wvp); bv = b_out + sum bvp
__global__ __launch_bounds__(256) void wvt_fin(const float* __restrict__ wvp,
                                               const float* __restrict__ bvp,
                                               const float* __restrict__ b_out,
                                               u16* __restrict__ wvTf,
                                               float* __restrict__ bv) {
  const int e = blockIdx.x;   // 512
  const int t = threadIdx.x;  // 256 = hm
  const int h = t >> 4, m = t & 15;
  float s = 0.f;
#pragma unroll
  for (int dc = 0; dc < 8; dc++)
    s += wvp[((size_t)(h * 8 + dc) * 512 + e) * 16 + m];
  wvTf[((((size_t)(t >> 3)) * 512 + e) << 3) + (t & 7)] = f2bf(s);
  if (t < 64) {
    float b = bvp[(size_t)t * 512 + e] + bvp[(size_t)(t + 64) * 512 + e];
#pragma unroll
    for (int mask = 32; mask >= 1; mask >>= 1) b += __shfl_xor(b, mask);
    if (t == 0) bv[e] = b_out[e] + b;
  }
}

// bk[hm] = b_mk[m] + sum_d b_in[h*128+d]*W_mk[d,m]
__global__ void prep_bk(const float* __restrict__ b_in, const float* __restrict__ wm,
                        const float* __restrict__ b_mk, float* __restrict__ bk) {
  const int t = threadIdx.x;
  const int h = t >> 4, m = t & 15;
  float acc = b_mk[m];
  for (int d = 0; d < 128; d++) acc += b_in[h * 128 + d] * wm[d * 16 + m];
  bk[t] = acc;
}

// ---------------------------------------------------------------------------
// GEMM A (round-13 structure, unchanged): BK=64 A-dbuf via global_load_lds,
// B per-lane frags from wkTf, fused colsum.
__global__ __launch_bounds__(256, 4) void gemm_a(const float* __restrict__ x,
                                                 const u16* __restrict__ wkTf,
                                                 const float* __restrict__ bk,
                                                 u16* __restrict__ logits,
                                                 float* __restrict__ cpart) {
  __shared__ float Asf[2][4096];  // 2 x 16 KB: 64 rows x 256 B (swizzled)
  __shared__ float cs[2][128];
  const int t = threadIdx.x;
  const int l = t & 63, w = t >> 6;
  const int wr = w >> 1, wc = w & 1;
  const int lrow = l & 15, lkg = l >> 4;
  const int gCol0 = blockIdx.x << 7;
  const int gRow0 = blockIdx.y << 6;

  const char* xb = (const char*)x;
  const char* gA[4]; int lAo[4];
#pragma unroll
  for (int p = 0; p < 4; p++) {
    const int o = p * 4096 + t * 16;              // phys byte 0..16383
    const int row = o >> 8, pin = o & 255;
    const int lin = pin ^ ((row & 7) << 5);       // logical byte in 256B row
    gA[p] = xb + (size_t)(gRow0 + row) * 2048 + lin;
    lAo[p] = o;
  }
  const int col0 = gCol0 + wc * 64 + lrow;        // + n*16

  f32x4 acc[2][4];
#pragma unroll
  for (int i = 0; i < 2; i++)
#pragma unroll
    for (int n = 0; n < 4; n++) acc[i][n] = f32x4{0.f, 0.f, 0.f, 0.f};

  uint4 bReg[2][4];
#pragma unroll
  for (int p = 0; p < 4; p++) gl16(gA[p], (char*)(&Asf[0][0]) + lAo[p]);
#pragma unroll
  for (int n = 0; n < 4; n++)
    bReg[0][n] = *(const uint4*)(wkTf + ((size_t)lkg * 256 + col0 + n * 16) * 8);
  __syncthreads();

  for (int kc = 0; kc < 8; ++kc) {
    const int buf = kc & 1;
    if (kc < 7) {
#pragma unroll
      for (int p = 0; p < 4; p++)
        gl16(gA[p] + (size_t)(kc + 1) * 256, (char*)(&Asf[buf ^ 1][0]) + lAo[p]);
    }
#pragma unroll
    for (int s = 0; s < 2; ++s) {
      const int nkc = (s == 0) ? kc : kc + 1;
      const int nss = s ^ 1;
      if (nkc < 8) {
#pragma unroll
        for (int n = 0; n < 4; n++)
          bReg[s ^ 1][n] = *(const uint4*)(
              wkTf + ((size_t)(nkc * 8 + nss * 4 + lkg) * 256 + col0 + n * 16) * 8);
      }
      s16x8 af[2];
#pragma unroll
      for (int i = 0; i < 2; i++) {
        const int r = wr * 32 + i * 16 + lrow;
        const int phys = (s * 128 + lkg * 32) ^ ((r & 7) << 5);
        const float4 a0 = *(const float4*)&Asf[buf][r * 64 + (phys >> 2)];
        const float4 a1 = *(const float4*)&Asf[buf][r * 64 + (phys >> 2) + 4];
        af[i] = as_s16x8(pack_bf8(a0, a1));
      }
#pragma unroll
      for (int n = 0; n < 4; n++) {
        const s16x8 bfr = as_s16x8(bReg[s][n]);
#pragma unroll
        for (int i = 0; i < 2; i++) mfma_bf16(acc[i][n], af[i], bfr);
      }
    }
    __syncthreads();
  }

  asm volatile("s_nop 7\n\ts_nop 7");
  const int crow = lkg * 4;
  float esum[4];
#pragma unroll
  for (int n = 0; n < 4; n++) {
    const int col = gCol0 + wc * 64 + n * 16 + lrow;
    const float bias = bk[col];
    float es = 0.f;
#pragma unroll
    for (int i = 0; i < 2; i++) {
      const int row0 = gRow0 + wr * 32 + i * 16 + crow;
#pragma unroll
      for (int j = 0; j < 4; j++) {
        const u16 q = f2bf(acc[i][n][j] + bias);
        logits[(size_t)(row0 + j) * 256 + col] = q;
        es += __expf(bf2f(q));
      }
    }
    esum[n] = es;
  }
#pragma unroll
  for (int n = 0; n < 4; n++) {
    esum[n] += __shfl_xor(esum[n], 16);
    esum[n] += __shfl_xor(esum[n], 32);
  }
  if (l < 16) {
#pragma unroll
    for (int n = 0; n < 4; n++) cs[wr][wc * 64 + n * 16 + l] = esum[n];
  }
  __syncthreads();
  if (t < 128)
    cpart[(size_t)blockIdx.y * 256 + gCol0 + t] = cs[0][t] + cs[1][t];
}

// inv[b][hm] = 1 / sum over the batch's 16 row-block partials
__global__ void colsum_fin(const float* __restrict__ cpart, float* __restrict__ inv) {
  const int b = blockIdx.x, hm = threadIdx.x;
  float s = 0.f;
#pragma unroll
  for (int k = 0; k < 16; k++) s += cpart[(size_t)(b * 16 + k) * 256 + hm];
  inv[b * 256 + hm] = 1.0f / s;
}

// ---------------------------------------------------------------------------
// GEMM B: out[32768,512] = P @ Wv + bv (fp32 out).
// Grid 256 blocks x 512 thr (8 waves); block = 128 rows x 512 cols.
// Wave owns 16 rows. Phase A: in-register softmax -> af[8] (r14-verified).
// Then 4 col-quarters: stage 64KB of wvTf into LDS [kg][col] cells
// (coalesced gl16; measured-0-conflict layout), barrier, MFMA from LDS,
// segmented stores. lg read once; B traffic 64 MB total.
__global__ __launch_bounds__(512, 2) void gemm_b(const u16* __restrict__ lg,
                                                 const float* __restrict__ inv,
                                                 const u16* __restrict__ wvTf,
                                                 const float* __restrict__ bvv,
                                                 float* __restrict__ out) {
  __shared__ u16 Bsh[32768];  // 64 KiB: cells [kg 0..31][col 0..127] of 16B
  const int t = threadIdx.x;
  const int l = t & 63, w = t >> 6;
  const int lrow = l & 15, lkg = l >> 4;
  const int gRow0 = blockIdx.x << 7;
  const int bIdx = blockIdx.x >> 3;   // 8 row-blocks per batch
  const int rowBase = gRow0 + w * 16;

  // ---- phase A: softmax -> af[8] in registers (verified in round 14) ----
  const u16* aBase = lg + (size_t)(rowBase + lrow) * 256 + lkg * 8;
  const float* ivB = inv + bIdx * 256 + lkg * 8;
  s16x8 af[8];
#pragma unroll
  for (int kc = 0; kc < 8; ++kc) {
    const uint4 q = *(const uint4*)(aBase + kc * 32);
    const float4 i0 = *(const float4*)(ivB + kc * 32);
    const float4 i1 = *(const float4*)(ivB + kc * 32 + 4);
    const float e0 = __expf(bf2f((u16)(q.x & 0xffffu))) * i0.x;
    const float e1 = __expf(bf2f((u16)(q.x >> 16)))     * i0.y;
    const float e2 = __expf(bf2f((u16)(q.y & 0xffffu))) * i0.z;
    const float e3 = __expf(bf2f((u16)(q.y >> 16)))     * i0.w;
    const float e4 = __expf(bf2f((u16)(q.z & 0xffffu))) * i1.x;
    const float e5 = __expf(bf2f((u16)(q.z >> 16)))     * i1.y;
    const float e6 = __expf(bf2f((u16)(q.w & 0xffffu))) * i1.z;
    const float e7 = __expf(bf2f((u16)(q.w >> 16)))     * i1.w;
    float s = ((e0 + e1) + (e2 + e3)) + ((e4 + e5) + (e6 + e7));
    s += __shfl_xor(s, 16);  // lkg 0<->1 (head 2kc), 2<->3 (head 2kc+1)
    const float rs = 1.0f / (s + 1e-9f);
    af[kc] = as_s16x8(make_uint4(cvt2(e0 * rs, e1 * rs), cvt2(e2 * rs, e3 * rs),
                                 cvt2(e4 * rs, e5 * rs), cvt2(e6 * rs, e7 * rs)));
  }

  // ---- 4 col-quarters: stage B -> LDS, MFMA, store ----
  for (int cq = 0; cq < 4; ++cq) {
    __syncthreads();  // prior quarter's Bsh reads complete
    // stage: 4096 cells / 512 thr = 8 gl16 each; lane-contiguous dest
#pragma unroll
    for (int i = 0; i < 8; ++i) {
      const int c = i * 512 + t;              // cell: kg = c>>7, col = c&127
      const int kg = c >> 7, col = c & 127;
      gl16(wvTf + ((size_t)kg * 512 + cq * 128 + col) * 8, (char*)Bsh + c * 16);
    }
    __syncthreads();  // vmcnt(0) drain: B tile visible

    f32x4 acc[8];
#pragma unroll
    for (int n = 0; n < 8; n++) acc[n] = f32x4{0.f, 0.f, 0.f, 0.f};

#pragma unroll
    for (int kc = 0; kc < 8; ++kc) {
      s16x8 bfr[8];
#pragma unroll
      for (int n = 0; n < 8; ++n)
        bfr[n] = *(const s16x8*)&Bsh[((kc * 4 + lkg) * 128 + n * 16 + lrow) * 8];
#pragma unroll
      for (int n = 0; n < 8; ++n) mfma_bf16(acc[n], af[kc], bfr[n]);
    }

    // stores: lane covers 4 rows (lkg*4+j) x 16 cols (n*16+lrow); 64B segs
#pragma unroll
    for (int n = 0; n < 8; ++n) {
      const int col = cq * 128 + n * 16 + lrow;
      const float bias = bvv[col];
#pragma unroll
      for (int j = 0; j < 4; ++j)
        out[(size_t)(rowBase + lkg * 4 + j) * 512 + col] = acc[n][j] + bias;
    }
  }
}

// ---------------------------------------------------------------------------
extern "C" void kernel_launch(void* const* d_in, const int* in_sizes, int n_in,
                              void* d_out, int out_size, void* d_ws, size_t ws_size,
                              hipStream_t stream) {
  (void)in_sizes; (void)n_in; (void)out_size; (void)ws_size;
  const float* x     = (const float*)d_in[0];
  const float* W_in  = (const float*)d_in[1];
  const float* b_in  = (const float*)d_in[2];
  const float* W_mk  = (const float*)d_in[3];
  const float* b_mk  = (const float*)d_in[4];
  const float* W_mv  = (const float*)d_in[5];
  const float* b_mv  = (const float*)d_in[6];
  const float* W_out = (const float*)d_in[7];
  const float* b_out = (const float*)d_in[8];

  char* ws = (char*)d_ws;
  u16*   wkTf = (u16*)(ws + OFF_WKT);
  u16*   wvTf = (u16*)(ws + OFF_WVT);
  float* bk   = (float*)(ws + OFF_BK);
  float* bv   = (float*)(ws + OFF_BV);
  float* inv  = (float*)(ws + OFF_INV);
  float* cp   = (float*)(ws + OFF_CP);
  u16*   lg   = (u16*)(ws + OFF_LOG);
  float* wvp  = (float*)(ws + OFF_WVP);
  float* bvp  = (float*)(ws + OFF_BVP);
  float* outp = (float*)d_out;

  prep_wkt<<<512, 256, 0, stream>>>(W_in, W_mk, wkTf);
  wvt_part<<<128, 256, 0, stream>>>(W_mv, b_mv, W_out, wvp, bvp);
  wvt_fin<<<512, 256, 0, stream>>>(wvp, bvp, b_out, wvTf, bv);
  prep_bk<<<1, 256, 0, stream>>>(b_in, W_mk, b_mk, bk);
  gemm_a<<<dim3(2, 512), 256, 0, stream>>>(x, wkTf, bk, lg, cp);
  colsum_fin<<<32, 256, 0, stream>>>(cp, inv);
  gemm_b<<<256, 512, 0, stream>>>(lg, inv, wvTf, bv, outp);
}

// Round 16
// 62.430 us; speedup vs baseline: 1.6543x; 1.2112x over previous
//
#include <hip/hip_runtime.h>
#include <cstdint>
#include <cstddef>

// ---------------------------------------------------------------------------
// MultiHeadExternalAttention, algebraically collapsed:
//   logits = x @ Wk + bk ; attn = softmax_n -> L1_m ; out = attn @ Wv + bv
// B=32 N=1024 E=512 H=16 M=16 HM=256 ROWS=32768
// Round 16 (consolidation): 9 kernels -> 4.
//  * prep_all = prep_wkt (blk 0..511) + wvt_part (512..639) + prep_bk (640).
//  * gemm_a: single col-pass (512 blk x 512 thr, 64r x 256c) -> x read ONCE.
//  * gemm_b: 512 blk x 512 thr (2 blk/CU = 16 waves/CU, was 8); colsum_fin
//    fused into prologue; in-register softmax (r15-verified); B dbuf-staged
//    per 4-kg chunk (2x32KB, coalesced gl16 from frag-contiguous wvTf).
// ---------------------------------------------------------------------------

typedef unsigned short u16;
typedef unsigned int u32;
typedef short s16x8 __attribute__((ext_vector_type(8)));
typedef float f32x4 __attribute__((ext_vector_type(4)));

// workspace layout (bytes)
constexpr size_t OFF_WKT  = 1u << 20;                 // u16 [64][256][8] (256 KiB)
constexpr size_t OFF_WVT  = OFF_WKT + (1u << 18);     // u16 [32][512][8] (256 KiB)
constexpr size_t OFF_BK   = OFF_WVT + (1u << 18);     // f32 [256]
constexpr size_t OFF_BV   = OFF_BK + 4096;            // f32 [512]
constexpr size_t OFF_CP   = 2u << 20;                 // f32 [512][256]
constexpr size_t OFF_LOG  = 4u << 20;                 // u16 [32768][256] (16 MiB)
constexpr size_t OFF_WVP  = 40u << 20;                // f32 partials (4 MiB)
constexpr size_t OFF_BVP  = 45u << 20;                // f32 partials (256 KiB)

__device__ __forceinline__ float bf2f(u16 v) {
  union { u32 u; float f; } c; c.u = ((u32)v) << 16; return c.f;
}
__device__ __forceinline__ u16 f2bf(float f) {
  union { float f; u32 u; } c; c.f = f;
  u32 u = c.u;
  u += 0x7fffu + ((u >> 16) & 1u);
  return (u16)(u >> 16);
}
__device__ __forceinline__ u32 cvt2(float lo, float hi) {
  u32 r;
  asm("v_cvt_pk_bf16_f32 %0, %1, %2" : "=v"(r) : "v"(lo), "v"(hi));
  return r;
}
__device__ __forceinline__ uint4 pack_bf8(float4 lo, float4 hi) {
  return make_uint4(cvt2(lo.x, lo.y), cvt2(lo.z, lo.w),
                    cvt2(hi.x, hi.y), cvt2(hi.z, hi.w));
}
__device__ __forceinline__ s16x8 as_s16x8(uint4 v) {
  union { uint4 u; s16x8 s; } c; c.u = v; return c.s;
}
__device__ __forceinline__ void mfma_bf16(f32x4& acc, s16x8 a, s16x8 b) {
  asm volatile("v_mfma_f32_16x16x32_bf16 %0, %1, %2, %0"
               : "+v"(acc) : "v"(a), "v"(b));
}
__device__ __forceinline__ void gl16(const void* g, void* l) {
  __builtin_amdgcn_global_load_lds(
      (const __attribute__((address_space(1))) void*)g,
      (__attribute__((address_space(3))) void*)l, 16, 0, 0);
}

// ---------------------------------------------------------------------------
// prep_all: blk 0..511 -> wkT_f; blk 512..639 -> wvt partials; blk 640 -> bk.
__global__ __launch_bounds__(256) void prep_all(
    const float* __restrict__ wi, const float* __restrict__ wm,
    const float* __restrict__ b_in, const float* __restrict__ b_mk,
    const float* __restrict__ mv, const float* __restrict__ b_mv,
    const float* __restrict__ wo,
    u16* __restrict__ wkTf, float* __restrict__ bkv,
    float* __restrict__ wvp, float* __restrict__ bvp) {
  const int t = threadIdx.x;
  if (blockIdx.x < 512) {
    // wkT_f[kg = e>>3][hm][idx = e&7] = sum_d W_in[e, h*128+d] * W_mk[d, m]
    const int gid = blockIdx.x * 256 + t;
    const int hm = gid & 255, e = gid >> 8;
    const int h = hm >> 4, m = hm & 15;
    float acc = 0.f;
    for (int d = 0; d < 128; d++)
      acc += wi[e * 2048 + h * 128 + d] * wm[d * 16 + m];
    wkTf[((((size_t)(e >> 3)) * 256 + hm) << 3) + (e & 7)] = f2bf(acc);
  } else if (blockIdx.x < 640) {
    // wvt partial: blk = (h, dc); 16 d's per chunk; coalesced W_out rows.
    __shared__ float wmv_l[16][16];
    __shared__ float bmv_l[16];
    const int blk = blockIdx.x - 512;
    const int h = blk >> 3, dc = blk & 7;
    {
      const int m = t >> 4, dd = t & 15;
      wmv_l[m][dd] = mv[m * 128 + dc * 16 + dd];
      if (t < 16) bmv_l[t] = b_mv[dc * 16 + t];
    }
    __syncthreads();
    float acc0[16], acc1[16];
    float bv0 = 0.f, bv1 = 0.f;
#pragma unroll
    for (int m = 0; m < 16; m++) { acc0[m] = 0.f; acc1[m] = 0.f; }
#pragma unroll
    for (int dd = 0; dd < 16; dd++) {
      const float w0 = wo[(size_t)(h * 128 + dc * 16 + dd) * 512 + t];
      const float w1 = wo[(size_t)(h * 128 + dc * 16 + dd) * 512 + 256 + t];
#pragma unroll
      for (int m = 0; m < 16; m++) {
        const float c = wmv_l[m][dd];
        acc0[m] += c * w0;
        acc1[m] += c * w1;
      }
      bv0 += bmv_l[dd] * w0;
      bv1 += bmv_l[dd] * w1;
    }
    float* w0p = wvp + ((size_t)blk * 512 + t) * 16;
    float* w1p = wvp + ((size_t)blk * 512 + 256 + t) * 16;
#pragma unroll
    for (int m = 0; m < 16; m++) { w0p[m] = acc0[m]; w1p[m] = acc1[m]; }
    bvp[(size_t)blk * 512 + t] = bv0;
    bvp[(size_t)blk * 512 + 256 + t] = bv1;
  } else {
    // bk[hm] = b_mk[m] + sum_d b_in[h*128+d]*W_mk[d,m]
    const int h = t >> 4, m = t & 15;
    float acc = b_mk[m];
    for (int d = 0; d < 128; d++) acc += b_in[h * 128 + d] * wm[d * 16 + m];
    bkv[t] = acc;
  }
}

// wvT_f[kg = hm>>3][e][idx = hm&7] = f2bf(sum_dc wvp); bv = b_out + sum bvp
__global__ __launch_bounds__(256) void wvt_fin(const float* __restrict__ wvp,
                                               const float* __restrict__ bvp,
                                               const float* __restrict__ b_out,
                                               u16* __restrict__ wvTf,
                                               float* __restrict__ bv) {
  const int e = blockIdx.x;   // 512
  const int t = threadIdx.x;  // 256 = hm
  const int h = t >> 4, m = t & 15;
  float s = 0.f;
#pragma unroll
  for (int dc = 0; dc < 8; dc++)
    s += wvp[((size_t)(h * 8 + dc) * 512 + e) * 16 + m];
  wvTf[((((size_t)(t >> 3)) * 512 + e) << 3) + (t & 7)] = f2bf(s);
  if (t < 64) {
    float b = bvp[(size_t)t * 512 + e] + bvp[(size_t)(t + 64) * 512 + e];
#pragma unroll
    for (int mask = 32; mask >= 1; mask >>= 1) b += __shfl_xor(b, mask);
    if (t == 0) bv[e] = b_out[e] + b;
  }
}

// ---------------------------------------------------------------------------
// GEMM A: logits[32768,256] = x @ Wk + bk (bf16) + colsum partials.
// Grid 512 blocks x 512 thr (8 waves 2x4); block = 64 rows x ALL 256 cols
// (x read ONCE). BK=64, A-dbuf 2x16KB via global_load_lds (32B-granule XOR
// swizzle via pre-swizzled source); B per-lane frags from frag-contiguous
// wkTf, substep depth-1 register prefetch. One __syncthreads per K-step.
__global__ __launch_bounds__(512, 2) void gemm_a(const float* __restrict__ x,
                                                 const u16* __restrict__ wkTf,
                                                 const float* __restrict__ bk,
                                                 u16* __restrict__ logits,
                                                 float* __restrict__ cpart) {
  __shared__ float Asf[2][4096];  // 2 x 16 KB: 64 rows x 256 B (swizzled)
  __shared__ float cs[2][256];
  const int t = threadIdx.x;
  const int l = t & 63, w = t >> 6;
  const int wr = w >> 2, wc = w & 3;
  const int lrow = l & 15, lkg = l >> 4;
  const int gRow0 = blockIdx.x << 6;

  const char* xb = (const char*)x;
  const char* gA[2]; int lAo[2];
#pragma unroll
  for (int p = 0; p < 2; p++) {
    const int o = p * 8192 + t * 16;              // phys byte 0..16383
    const int row = o >> 8, pin = o & 255;
    const int lin = pin ^ ((row & 7) << 5);       // logical byte in 256B row
    gA[p] = xb + (size_t)(gRow0 + row) * 2048 + lin;
    lAo[p] = o;
  }
  const int col0 = wc * 64 + lrow;                // + n*16

  f32x4 acc[2][4];
#pragma unroll
  for (int i = 0; i < 2; i++)
#pragma unroll
    for (int n = 0; n < 4; n++) acc[i][n] = f32x4{0.f, 0.f, 0.f, 0.f};

  uint4 bReg[2][4];
#pragma unroll
  for (int p = 0; p < 2; p++) gl16(gA[p], (char*)(&Asf[0][0]) + lAo[p]);
#pragma unroll
  for (int n = 0; n < 4; n++)
    bReg[0][n] = *(const uint4*)(wkTf + ((size_t)lkg * 256 + col0 + n * 16) * 8);
  __syncthreads();

  for (int kc = 0; kc < 8; ++kc) {
    const int buf = kc & 1;
    if (kc < 7) {
#pragma unroll
      for (int p = 0; p < 2; p++)
        gl16(gA[p] + (size_t)(kc + 1) * 256, (char*)(&Asf[buf ^ 1][0]) + lAo[p]);
    }
#pragma unroll
    for (int s = 0; s < 2; ++s) {
      const int nkc = (s == 0) ? kc : kc + 1;
      const int nss = s ^ 1;
      if (nkc < 8) {
#pragma unroll
        for (int n = 0; n < 4; n++)
          bReg[s ^ 1][n] = *(const uint4*)(
              wkTf + ((size_t)(nkc * 8 + nss * 4 + lkg) * 256 + col0 + n * 16) * 8);
      }
      s16x8 af[2];
#pragma unroll
      for (int i = 0; i < 2; i++) {
        const int r = wr * 32 + i * 16 + lrow;
        const int phys = (s * 128 + lkg * 32) ^ ((r & 7) << 5);
        const float4 a0 = *(const float4*)&Asf[buf][r * 64 + (phys >> 2)];
        const float4 a1 = *(const float4*)&Asf[buf][r * 64 + (phys >> 2) + 4];
        af[i] = as_s16x8(pack_bf8(a0, a1));
      }
#pragma unroll
      for (int n = 0; n < 4; n++) {
        const s16x8 bfr = as_s16x8(bReg[s][n]);
#pragma unroll
        for (int i = 0; i < 2; i++) mfma_bf16(acc[i][n], af[i], bfr);
      }
    }
    __syncthreads();
  }

  asm volatile("s_nop 7\n\ts_nop 7");
  const int crow = lkg * 4;  // C/D: row = (l>>4)*4 + j, col = l&15
  float esum[4];
#pragma unroll
  for (int n = 0; n < 4; n++) {
    const int col = wc * 64 + n * 16 + lrow;
    const float bias = bk[col];
    float es = 0.f;
#pragma unroll
    for (int i = 0; i < 2; i++) {
      const int row0 = gRow0 + wr * 32 + i * 16 + crow;
#pragma unroll
      for (int j = 0; j < 4; j++) {
        const u16 q = f2bf(acc[i][n][j] + bias);
        logits[(size_t)(row0 + j) * 256 + col] = q;
        es += __expf(bf2f(q));
      }
    }
    esum[n] = es;
  }
#pragma unroll
  for (int n = 0; n < 4; n++) {
    esum[n] += __shfl_xor(esum[n], 16);
    esum[n] += __shfl_xor(esum[n], 32);
  }
  if (l < 16) {
#pragma unroll
    for (int n = 0; n < 4; n++) cs[wr][wc * 64 + n * 16 + l] = esum[n];
  }
  __syncthreads();
  if (t < 256)
    cpart[(size_t)blockIdx.x * 256 + t] = cs[0][t] + cs[1][t];
}

// ---------------------------------------------------------------------------
// GEMM B: out[32768,512] = P @ Wv + bv (fp32 out). colsum_fin FUSED.
// Grid 512 blocks x 512 thr (8 waves = 4 rowg x 2 colhalf; 2 blk/CU =
// 16 waves/CU); block = 64 rows x ALL 512 cols.
// Prologue: inv[256] from cpart into LDS. Phase A: per-wave in-register
// softmax -> af[8] (r15-verified; iv from LDS). K-loop: B dbuf 2x32KB
// ([kg 0..3][col 0..511] cells) staged with perfectly-coalesced gl16 from
// frag-contiguous wvTf; stage(kc+1) issued before compute(kc); 16 MFMA.
__global__ __launch_bounds__(512, 2) void gemm_b(const u16* __restrict__ lg,
                                                 const float* __restrict__ cpart,
                                                 const u16* __restrict__ wvTf,
                                                 const float* __restrict__ bvv,
                                                 float* __restrict__ out) {
  __shared__ u16 Bsh[2][16384];  // 2 x 32 KB
  __shared__ float invl[256];
  const int t = threadIdx.x;
  const int l = t & 63, w = t >> 6;
  const int lrow = l & 15, lkg = l >> 4;
  const int rowg = w >> 1, ch = w & 1;
  const int gRow0 = blockIdx.x << 6;
  const int bIdx = blockIdx.x >> 4;   // 16 row-blocks per batch
  const int rowBase = gRow0 + rowg * 16;

  // fused colsum_fin: inv into LDS
  if (t < 256) {
    float s = 0.f;
#pragma unroll
    for (int k = 0; k < 16; k++) s += cpart[(size_t)(bIdx * 16 + k) * 256 + t];
    invl[t] = 1.0f / s;
  }
  __syncthreads();

  // issue stage(kc=0) early — overlaps with phase A's lg loads
#pragma unroll
  for (int i = 0; i < 4; ++i) {
    const int c = i * 512 + t;                 // cell: kgl = c>>9, e = c&511
    gl16(wvTf + (size_t)c * 8, (char*)(&Bsh[0][0]) + c * 16);
  }

  // ---- phase A: softmax -> af[8] in registers ----
  const u16* aBase = lg + (size_t)(rowBase + lrow) * 256 + lkg * 8;
  s16x8 af[8];
#pragma unroll
  for (int kc = 0; kc < 8; ++kc) {
    const uint4 q = *(const uint4*)(aBase + kc * 32);
    const float4 i0 = *(const float4*)&invl[kc * 32 + lkg * 8];
    const float4 i1 = *(const float4*)&invl[kc * 32 + lkg * 8 + 4];
    const float e0 = __expf(bf2f((u16)(q.x & 0xffffu))) * i0.x;
    const float e1 = __expf(bf2f((u16)(q.x >> 16)))     * i0.y;
    const float e2 = __expf(bf2f((u16)(q.y & 0xffffu))) * i0.z;
    const float e3 = __expf(bf2f((u16)(q.y >> 16)))     * i0.w;
    const float e4 = __expf(bf2f((u16)(q.z & 0xffffu))) * i1.x;
    const float e5 = __expf(bf2f((u16)(q.z >> 16)))     * i1.y;
    const float e6 = __expf(bf2f((u16)(q.w & 0xffffu))) * i1.z;
    const float e7 = __expf(bf2f((u16)(q.w >> 16)))     * i1.w;
    float s = ((e0 + e1) + (e2 + e3)) + ((e4 + e5) + (e6 + e7));
    s += __shfl_xor(s, 16);  // lkg 0<->1 (head 2kc), 2<->3 (head 2kc+1)
    const float rs = 1.0f / (s + 1e-9f);
    af[kc] = as_s16x8(make_uint4(cvt2(e0 * rs, e1 * rs), cvt2(e2 * rs, e3 * rs),
                                 cvt2(e4 * rs, e5 * rs), cvt2(e6 * rs, e7 * rs)));
  }
  __syncthreads();  // vmcnt(0): Bsh[0] staged; all waves past phase A

  f32x4 acc[16];
#pragma unroll
  for (int n = 0; n < 16; n++) acc[n] = f32x4{0.f, 0.f, 0.f, 0.f};

  for (int kc = 0; kc < 8; ++kc) {
    const int buf = kc & 1;
    if (kc < 7) {
#pragma unroll
      for (int i = 0; i < 4; ++i) {
        const int c = i * 512 + t;
        gl16(wvTf + ((size_t)(kc + 1) * 2048 + c) * 8,
             (char*)(&Bsh[buf ^ 1][0]) + c * 16);
      }
    }
#pragma unroll
    for (int n = 0; n < 16; ++n) {
      const s16x8 bfr = *(const s16x8*)
          &Bsh[buf][((lkg * 512 + ch * 256 + n * 16 + lrow)) * 8];
      mfma_bf16(acc[n], af[kc], bfr);
    }
    __syncthreads();  // vmcnt(0): next chunk staged; buf reads complete
  }

  asm volatile("s_nop 7\n\ts_nop 7");
  // stores: lane covers 4 rows (lkg*4+j) x 16 cols per n; 64B segments
#pragma unroll
  for (int n = 0; n < 16; ++n) {
    const int col = ch * 256 + n * 16 + lrow;
    const float bias = bvv[col];
#pragma unroll
    for (int j = 0; j < 4; ++j)
      out[(size_t)(rowBase + lkg * 4 + j) * 512 + col] = acc[n][j] + bias;
  }
}

// ---------------------------------------------------------------------------
extern "C" void kernel_launch(void* const* d_in, const int* in_sizes, int n_in,
                              void* d_out, int out_size, void* d_ws, size_t ws_size,
                              hipStream_t stream) {
  (void)in_sizes; (void)n_in; (void)out_size; (void)ws_size;
  const float* x     = (const float*)d_in[0];
  const float* W_in  = (const float*)d_in[1];
  const float* b_in  = (const float*)d_in[2];
  const float* W_mk  = (const float*)d_in[3];
  const float* b_mk  = (const float*)d_in[4];
  const float* W_mv  = (const float*)d_in[5];
  const float* b_mv  = (const float*)d_in[6];
  const float* W_out = (const float*)d_in[7];
  const float* b_out = (const float*)d_in[8];

  char* ws = (char*)d_ws;
  u16*   wkTf = (u16*)(ws + OFF_WKT);
  u16*   wvTf = (u16*)(ws + OFF_WVT);
  float* bk   = (float*)(ws + OFF_BK);
  float* bv   = (float*)(ws + OFF_BV);
  float* cp   = (float*)(ws + OFF_CP);
  u16*   lg   = (u16*)(ws + OFF_LOG);
  float* wvp  = (float*)(ws + OFF_WVP);
  float* bvp  = (float*)(ws + OFF_BVP);
  float* outp = (float*)d_out;

  prep_all<<<641, 256, 0, stream>>>(W_in, W_mk, b_in, b_mk, W_mv, b_mv, W_out,
                                    wkTf, bk, wvp, bvp);
  wvt_fin<<<512, 256, 0, stream>>>(wvp, bvp, b_out, wvTf, bv);
  gemm_a<<<512, 512, 0, stream>>>(x, wkTf, bk, lg, cp);
  gemm_b<<<512, 512, 0, stream>>>(lg, cp, wvTf, bv, outp);
}

// Round 17
// 61.113 us; speedup vs baseline: 1.6899x; 1.0215x over previous
//
#include <hip/hip_runtime.h>
#include <cstdint>
#include <cstddef>

// ---------------------------------------------------------------------------
// MultiHeadExternalAttention, algebraically collapsed:
//   logits = x @ Wk + bk ; attn = softmax_n -> L1_m ; out = attn @ Wv + bv
// B=32 N=1024 E=512 H=16 M=16 HM=256 ROWS=32768
// Round 17: gemm_a re-tiled 64r -> 32r (1024 blocks x 256 thr): ~4-5 blk/CU
// co-resident (was 2) to hide the per-K-step vmcnt drain; waves own disjoint
// cols -> colsum epilogue loses its LDS reduce + barrier. gemm_b unchanged
// except fused colsum reads 32 cpart chunks. prep_all/wvt_fin unchanged.
// ---------------------------------------------------------------------------

typedef unsigned short u16;
typedef unsigned int u32;
typedef short s16x8 __attribute__((ext_vector_type(8)));
typedef float f32x4 __attribute__((ext_vector_type(4)));

// workspace layout (bytes)
constexpr size_t OFF_WKT  = 1u << 20;                 // u16 [64][256][8] (256 KiB)
constexpr size_t OFF_WVT  = OFF_WKT + (1u << 18);     // u16 [32][512][8] (256 KiB)
constexpr size_t OFF_BK   = OFF_WVT + (1u << 18);     // f32 [256]
constexpr size_t OFF_BV   = OFF_BK + 4096;            // f32 [512]
constexpr size_t OFF_CP   = 2u << 20;                 // f32 [1024][256] (1 MiB)
constexpr size_t OFF_LOG  = 4u << 20;                 // u16 [32768][256] (16 MiB)
constexpr size_t OFF_WVP  = 40u << 20;                // f32 partials (4 MiB)
constexpr size_t OFF_BVP  = 45u << 20;                // f32 partials (256 KiB)

__device__ __forceinline__ float bf2f(u16 v) {
  union { u32 u; float f; } c; c.u = ((u32)v) << 16; return c.f;
}
__device__ __forceinline__ u16 f2bf(float f) {
  union { float f; u32 u; } c; c.f = f;
  u32 u = c.u;
  u += 0x7fffu + ((u >> 16) & 1u);
  return (u16)(u >> 16);
}
__device__ __forceinline__ u32 cvt2(float lo, float hi) {
  u32 r;
  asm("v_cvt_pk_bf16_f32 %0, %1, %2" : "=v"(r) : "v"(lo), "v"(hi));
  return r;
}
__device__ __forceinline__ uint4 pack_bf8(float4 lo, float4 hi) {
  return make_uint4(cvt2(lo.x, lo.y), cvt2(lo.z, lo.w),
                    cvt2(hi.x, hi.y), cvt2(hi.z, hi.w));
}
__device__ __forceinline__ s16x8 as_s16x8(uint4 v) {
  union { uint4 u; s16x8 s; } c; c.u = v; return c.s;
}
__device__ __forceinline__ void mfma_bf16(f32x4& acc, s16x8 a, s16x8 b) {
  asm volatile("v_mfma_f32_16x16x32_bf16 %0, %1, %2, %0"
               : "+v"(acc) : "v"(a), "v"(b));
}
__device__ __forceinline__ void gl16(const void* g, void* l) {
  __builtin_amdgcn_global_load_lds(
      (const __attribute__((address_space(1))) void*)g,
      (__attribute__((address_space(3))) void*)l, 16, 0, 0);
}

// ---------------------------------------------------------------------------
// prep_all: blk 0..511 -> wkT_f; blk 512..639 -> wvt partials; blk 640 -> bk.
__global__ __launch_bounds__(256) void prep_all(
    const float* __restrict__ wi, const float* __restrict__ wm,
    const float* __restrict__ b_in, const float* __restrict__ b_mk,
    const float* __restrict__ mv, const float* __restrict__ b_mv,
    const float* __restrict__ wo,
    u16* __restrict__ wkTf, float* __restrict__ bkv,
    float* __restrict__ wvp, float* __restrict__ bvp) {
  const int t = threadIdx.x;
  if (blockIdx.x < 512) {
    const int gid = blockIdx.x * 256 + t;
    const int hm = gid & 255, e = gid >> 8;
    const int h = hm >> 4, m = hm & 15;
    float acc = 0.f;
    for (int d = 0; d < 128; d++)
      acc += wi[e * 2048 + h * 128 + d] * wm[d * 16 + m];
    wkTf[((((size_t)(e >> 3)) * 256 + hm) << 3) + (e & 7)] = f2bf(acc);
  } else if (blockIdx.x < 640) {
    __shared__ float wmv_l[16][16];
    __shared__ float bmv_l[16];
    const int blk = blockIdx.x - 512;
    const int h = blk >> 3, dc = blk & 7;
    {
      const int m = t >> 4, dd = t & 15;
      wmv_l[m][dd] = mv[m * 128 + dc * 16 + dd];
      if (t < 16) bmv_l[t] = b_mv[dc * 16 + t];
    }
    __syncthreads();
    float acc0[16], acc1[16];
    float bv0 = 0.f, bv1 = 0.f;
#pragma unroll
    for (int m = 0; m < 16; m++) { acc0[m] = 0.f; acc1[m] = 0.f; }
#pragma unroll
    for (int dd = 0; dd < 16; dd++) {
      const float w0 = wo[(size_t)(h * 128 + dc * 16 + dd) * 512 + t];
      const float w1 = wo[(size_t)(h * 128 + dc * 16 + dd) * 512 + 256 + t];
#pragma unroll
      for (int m = 0; m < 16; m++) {
        const float c = wmv_l[m][dd];
        acc0[m] += c * w0;
        acc1[m] += c * w1;
      }
      bv0 += bmv_l[dd] * w0;
      bv1 += bmv_l[dd] * w1;
    }
    float* w0p = wvp + ((size_t)blk * 512 + t) * 16;
    float* w1p = wvp + ((size_t)blk * 512 + 256 + t) * 16;
#pragma unroll
    for (int m = 0; m < 16; m++) { w0p[m] = acc0[m]; w1p[m] = acc1[m]; }
    bvp[(size_t)blk * 512 + t] = bv0;
    bvp[(size_t)blk * 512 + 256 + t] = bv1;
  } else {
    const int h = t >> 4, m = t & 15;
    float acc = b_mk[m];
    for (int d = 0; d < 128; d++) acc += b_in[h * 128 + d] * wm[d * 16 + m];
    bkv[t] = acc;
  }
}

// wvT_f[kg = hm>>3][e][idx = hm&7] = f2bf(sum_dc wvp); bv = b_out + sum bvp
__global__ __launch_bounds__(256) void wvt_fin(const float* __restrict__ wvp,
                                               const float* __restrict__ bvp,
                                               const float* __restrict__ b_out,
                                               u16* __restrict__ wvTf,
                                               float* __restrict__ bv) {
  const int e = blockIdx.x;   // 512
  const int t = threadIdx.x;  // 256 = hm
  const int h = t >> 4, m = t & 15;
  float s = 0.f;
#pragma unroll
  for (int dc = 0; dc < 8; dc++)
    s += wvp[((size_t)(h * 8 + dc) * 512 + e) * 16 + m];
  wvTf[((((size_t)(t >> 3)) * 512 + e) << 3) + (t & 7)] = f2bf(s);
  if (t < 64) {
    float b = bvp[(size_t)t * 512 + e] + bvp[(size_t)(t + 64) * 512 + e];
#pragma unroll
    for (int mask = 32; mask >= 1; mask >>= 1) b += __shfl_xor(b, mask);
    if (t == 0) bv[e] = b_out[e] + b;
  }
}

// ---------------------------------------------------------------------------
// GEMM A: logits[32768,256] = x @ Wk + bk (bf16) + colsum partials.
// Grid 1024 blocks x 256 thr (4 waves; wave = 32r x 64c, acc[2][4]).
// Block = 32 rows x ALL 256 cols; x read once; ~4-5 blk/CU co-resident.
// BK=64, A-dbuf 2x8KB via global_load_lds (32B-granule XOR swizzle via
// pre-swizzled source); B per-lane frags from frag-contiguous wkTf with
// substep depth-1 register prefetch. One __syncthreads per K-step.
// Waves own disjoint cols -> epilogue colsum needs no LDS/barrier.
__global__ __launch_bounds__(256, 2) void gemm_a(const float* __restrict__ x,
                                                 const u16* __restrict__ wkTf,
                                                 const float* __restrict__ bk,
                                                 u16* __restrict__ logits,
                                                 float* __restrict__ cpart) {
  __shared__ float Asf[2][2048];  // 2 x 8 KB: 32 rows x 256 B (swizzled)
  const int t = threadIdx.x;
  const int l = t & 63, w = t >> 6;
  const int lrow = l & 15, lkg = l >> 4;
  const int gRow0 = blockIdx.x << 5;

  const char* xb = (const char*)x;
  const char* gA[2]; int lAo[2];
#pragma unroll
  for (int p = 0; p < 2; p++) {
    const int o = p * 4096 + t * 16;              // phys byte 0..8191
    const int row = o >> 8, pin = o & 255;
    const int lin = pin ^ ((row & 7) << 5);       // logical byte in 256B row
    gA[p] = xb + (size_t)(gRow0 + row) * 2048 + lin;
    lAo[p] = o;
  }
  const int col0 = w * 64 + lrow;                 // + n*16

  f32x4 acc[2][4];
#pragma unroll
  for (int i = 0; i < 2; i++)
#pragma unroll
    for (int n = 0; n < 4; n++) acc[i][n] = f32x4{0.f, 0.f, 0.f, 0.f};

  uint4 bReg[2][4];
#pragma unroll
  for (int p = 0; p < 2; p++) gl16(gA[p], (char*)(&Asf[0][0]) + lAo[p]);
#pragma unroll
  for (int n = 0; n < 4; n++)
    bReg[0][n] = *(const uint4*)(wkTf + ((size_t)lkg * 256 + col0 + n * 16) * 8);
  __syncthreads();

  for (int kc = 0; kc < 8; ++kc) {
    const int buf = kc & 1;
    if (kc < 7) {
#pragma unroll
      for (int p = 0; p < 2; p++)
        gl16(gA[p] + (size_t)(kc + 1) * 256, (char*)(&Asf[buf ^ 1][0]) + lAo[p]);
    }
#pragma unroll
    for (int s = 0; s < 2; ++s) {
      const int nkc = (s == 0) ? kc : kc + 1;
      const int nss = s ^ 1;
      if (nkc < 8) {
#pragma unroll
        for (int n = 0; n < 4; n++)
          bReg[s ^ 1][n] = *(const uint4*)(
              wkTf + ((size_t)(nkc * 8 + nss * 4 + lkg) * 256 + col0 + n * 16) * 8);
      }
      s16x8 af[2];
#pragma unroll
      for (int i = 0; i < 2; i++) {
        const int r = i * 16 + lrow;
        const int phys = (s * 128 + lkg * 32) ^ ((r & 7) << 5);
        const float4 a0 = *(const float4*)&Asf[buf][r * 64 + (phys >> 2)];
        const float4 a1 = *(const float4*)&Asf[buf][r * 64 + (phys >> 2) + 4];
        af[i] = as_s16x8(pack_bf8(a0, a1));
      }
#pragma unroll
      for (int n = 0; n < 4; n++) {
        const s16x8 bfr = as_s16x8(bReg[s][n]);
#pragma unroll
        for (int i = 0; i < 2; i++) mfma_bf16(acc[i][n], af[i], bfr);
      }
    }
    __syncthreads();
  }

  asm volatile("s_nop 7\n\ts_nop 7");
  const int crow = lkg * 4;  // C/D: row = (l>>4)*4 + j, col = l&15
  float esum[4];
#pragma unroll
  for (int n = 0; n < 4; n++) {
    const int col = w * 64 + n * 16 + lrow;
    const float bias = bk[col];
    float es = 0.f;
#pragma unroll
    for (int i = 0; i < 2; i++) {
      const int row0 = gRow0 + i * 16 + crow;
#pragma unroll
      for (int j = 0; j < 4; j++) {
        const u16 q = f2bf(acc[i][n][j] + bias);
        logits[(size_t)(row0 + j) * 256 + col] = q;
        es += __expf(bf2f(q));
      }
    }
    esum[n] = es;
  }
#pragma unroll
  for (int n = 0; n < 4; n++) {
    esum[n] += __shfl_xor(esum[n], 16);
    esum[n] += __shfl_xor(esum[n], 32);
  }
  if (l < 16) {
#pragma unroll
    for (int n = 0; n < 4; n++)
      cpart[(size_t)blockIdx.x * 256 + w * 64 + n * 16 + l] = esum[n];
  }
}

// ---------------------------------------------------------------------------
// GEMM B: out[32768,512] = P @ Wv + bv (fp32 out). colsum_fin FUSED (32
// cpart chunks per batch now). Structure unchanged from round 16.
__global__ __launch_bounds__(512, 2) void gemm_b(const u16* __restrict__ lg,
                                                 const float* __restrict__ cpart,
                                                 const u16* __restrict__ wvTf,
                                                 const float* __restrict__ bvv,
                                                 float* __restrict__ out) {
  __shared__ u16 Bsh[2][16384];  // 2 x 32 KB
  __shared__ float invl[256];
  const int t = threadIdx.x;
  const int l = t & 63, w = t >> 6;
  const int lrow = l & 15, lkg = l >> 4;
  const int rowg = w >> 1, ch = w & 1;
  const int gRow0 = blockIdx.x << 6;
  const int bIdx = blockIdx.x >> 4;   // 16 row-blocks (64r) per batch
  const int rowBase = gRow0 + rowg * 16;

  // fused colsum_fin: inv into LDS (batch = 32 cpart chunks of 32 rows)
  if (t < 256) {
    float s = 0.f;
#pragma unroll
    for (int k = 0; k < 32; k++) s += cpart[(size_t)(bIdx * 32 + k) * 256 + t];
    invl[t] = 1.0f / s;
  }
  __syncthreads();

  // issue stage(kc=0) early — overlaps with phase A's lg loads
#pragma unroll
  for (int i = 0; i < 4; ++i) {
    const int c = i * 512 + t;                 // cell: kgl = c>>9, e = c&511
    gl16(wvTf + (size_t)c * 8, (char*)(&Bsh[0][0]) + c * 16);
  }

  // ---- phase A: softmax -> af[8] in registers ----
  const u16* aBase = lg + (size_t)(rowBase + lrow) * 256 + lkg * 8;
  s16x8 af[8];
#pragma unroll
  for (int kc = 0; kc < 8; ++kc) {
    const uint4 q = *(const uint4*)(aBase + kc * 32);
    const float4 i0 = *(const float4*)&invl[kc * 32 + lkg * 8];
    const float4 i1 = *(const float4*)&invl[kc * 32 + lkg * 8 + 4];
    const float e0 = __expf(bf2f((u16)(q.x & 0xffffu))) * i0.x;
    const float e1 = __expf(bf2f((u16)(q.x >> 16)))     * i0.y;
    const float e2 = __expf(bf2f((u16)(q.y & 0xffffu))) * i0.z;
    const float e3 = __expf(bf2f((u16)(q.y >> 16)))     * i0.w;
    const float e4 = __expf(bf2f((u16)(q.z & 0xffffu))) * i1.x;
    const float e5 = __expf(bf2f((u16)(q.z >> 16)))     * i1.y;
    const float e6 = __expf(bf2f((u16)(q.w & 0xffffu))) * i1.z;
    const float e7 = __expf(bf2f((u16)(q.w >> 16)))     * i1.w;
    float s = ((e0 + e1) + (e2 + e3)) + ((e4 + e5) + (e6 + e7));
    s += __shfl_xor(s, 16);  // lkg 0<->1 (head 2kc), 2<->3 (head 2kc+1)
    const float rs = 1.0f / (s + 1e-9f);
    af[kc] = as_s16x8(make_uint4(cvt2(e0 * rs, e1 * rs), cvt2(e2 * rs, e3 * rs),
                                 cvt2(e4 * rs, e5 * rs), cvt2(e6 * rs, e7 * rs)));
  }
  __syncthreads();  // vmcnt(0): Bsh[0] staged; all waves past phase A

  f32x4 acc[16];
#pragma unroll
  for (int n = 0; n < 16; n++) acc[n] = f32x4{0.f, 0.f, 0.f, 0.f};

  for (int kc = 0; kc < 8; ++kc) {
    const int buf = kc & 1;
    if (kc < 7) {
#pragma unroll
      for (int i = 0; i < 4; ++i) {
        const int c = i * 512 + t;
        gl16(wvTf + ((size_t)(kc + 1) * 2048 + c) * 8,
             (char*)(&Bsh[buf ^ 1][0]) + c * 16);
      }
    }
#pragma unroll
    for (int n = 0; n < 16; ++n) {
      const s16x8 bfr = *(const s16x8*)
          &Bsh[buf][((lkg * 512 + ch * 256 + n * 16 + lrow)) * 8];
      mfma_bf16(acc[n], af[kc], bfr);
    }
    __syncthreads();  // vmcnt(0): next chunk staged; buf reads complete
  }

  asm volatile("s_nop 7\n\ts_nop 7");
#pragma unroll
  for (int n = 0; n < 16; ++n) {
    const int col = ch * 256 + n * 16 + lrow;
    const float bias = bvv[col];
#pragma unroll
    for (int j = 0; j < 4; ++j)
      out[(size_t)(rowBase + lkg * 4 + j) * 512 + col] = acc[n][j] + bias;
  }
}

// ---------------------------------------------------------------------------
extern "C" void kernel_launch(void* const* d_in, const int* in_sizes, int n_in,
                              void* d_out, int out_size, void* d_ws, size_t ws_size,
                              hipStream_t stream) {
  (void)in_sizes; (void)n_in; (void)out_size; (void)ws_size;
  const float* x     = (const float*)d_in[0];
  const float* W_in  = (const float*)d_in[1];
  const float* b_in  = (const float*)d_in[2];
  const float* W_mk  = (const float*)d_in[3];
  const float* b_mk  = (const float*)d_in[4];
  const float* W_mv  = (const float*)d_in[5];
  const float* b_mv  = (const float*)d_in[6];
  const float* W_out = (const float*)d_in[7];
  const float* b_out = (const float*)d_in[8];

  char* ws = (char*)d_ws;
  u16*   wkTf = (u16*)(ws + OFF_WKT);
  u16*   wvTf = (u16*)(ws + OFF_WVT);
  float* bk   = (float*)(ws + OFF_BK);
  float* bv   = (float*)(ws + OFF_BV);
  float* cp   = (float*)(ws + OFF_CP);
  u16*   lg   = (u16*)(ws + OFF_LOG);
  float* wvp  = (float*)(ws + OFF_WVP);
  float* bvp  = (float*)(ws + OFF_BVP);
  float* outp = (float*)d_out;

  prep_all<<<641, 256, 0, stream>>>(W_in, W_mk, b_in, b_mk, W_mv, b_mv, W_out,
                                    wkTf, bk, wvp, bvp);
  wvt_fin<<<512, 256, 0, stream>>>(wvp, bvp, b_out, wvTf, bv);
  gemm_a<<<1024, 256, 0, stream>>>(x, wkTf, bk, lg, cp);
  gemm_b<<<512, 512, 0, stream>>>(lg, cp, wvTf, bv, outp);
}

// Round 18
// 58.119 us; speedup vs baseline: 1.7770x; 1.0515x over previous
//
#include <hip/hip_runtime.h>
#include <cstdint>
#include <cstddef>

// ---------------------------------------------------------------------------
// MultiHeadExternalAttention, algebraically collapsed:
//   logits = x @ Wk + bk ; attn = softmax_n -> L1_m ; out = attn @ Wv + bv
// B=32 N=1024 E=512 H=16 M=16 HM=256 ROWS=32768
// Round 18: wvt_fin merged into gemm_a's grid (blocks 1024..1535) — kernel
// count 4 -> 3; wvt_fin's 2us hides inside gemm_a. All else identical to r17.
// ---------------------------------------------------------------------------

typedef unsigned short u16;
typedef unsigned int u32;
typedef short s16x8 __attribute__((ext_vector_type(8)));
typedef float f32x4 __attribute__((ext_vector_type(4)));

// workspace layout (bytes)
constexpr size_t OFF_WKT  = 1u << 20;                 // u16 [64][256][8] (256 KiB)
constexpr size_t OFF_WVT  = OFF_WKT + (1u << 18);     // u16 [32][512][8] (256 KiB)
constexpr size_t OFF_BK   = OFF_WVT + (1u << 18);     // f32 [256]
constexpr size_t OFF_BV   = OFF_BK + 4096;            // f32 [512]
constexpr size_t OFF_CP   = 2u << 20;                 // f32 [1024][256] (1 MiB)
constexpr size_t OFF_LOG  = 4u << 20;                 // u16 [32768][256] (16 MiB)
constexpr size_t OFF_WVP  = 40u << 20;                // f32 partials (4 MiB)
constexpr size_t OFF_BVP  = 45u << 20;                // f32 partials (256 KiB)

__device__ __forceinline__ float bf2f(u16 v) {
  union { u32 u; float f; } c; c.u = ((u32)v) << 16; return c.f;
}
__device__ __forceinline__ u16 f2bf(float f) {
  union { float f; u32 u; } c; c.f = f;
  u32 u = c.u;
  u += 0x7fffu + ((u >> 16) & 1u);
  return (u16)(u >> 16);
}
__device__ __forceinline__ u32 cvt2(float lo, float hi) {
  u32 r;
  asm("v_cvt_pk_bf16_f32 %0, %1, %2" : "=v"(r) : "v"(lo), "v"(hi));
  return r;
}
__device__ __forceinline__ uint4 pack_bf8(float4 lo, float4 hi) {
  return make_uint4(cvt2(lo.x, lo.y), cvt2(lo.z, lo.w),
                    cvt2(hi.x, hi.y), cvt2(hi.z, hi.w));
}
__device__ __forceinline__ s16x8 as_s16x8(uint4 v) {
  union { uint4 u; s16x8 s; } c; c.u = v; return c.s;
}
__device__ __forceinline__ void mfma_bf16(f32x4& acc, s16x8 a, s16x8 b) {
  asm volatile("v_mfma_f32_16x16x32_bf16 %0, %1, %2, %0"
               : "+v"(acc) : "v"(a), "v"(b));
}
__device__ __forceinline__ void gl16(const void* g, void* l) {
  __builtin_amdgcn_global_load_lds(
      (const __attribute__((address_space(1))) void*)g,
      (__attribute__((address_space(3))) void*)l, 16, 0, 0);
}

// ---------------------------------------------------------------------------
// prep_all: blk 0..511 -> wkT_f; blk 512..639 -> wvt partials; blk 640 -> bk.
__global__ __launch_bounds__(256) void prep_all(
    const float* __restrict__ wi, const float* __restrict__ wm,
    const float* __restrict__ b_in, const float* __restrict__ b_mk,
    const float* __restrict__ mv, const float* __restrict__ b_mv,
    const float* __restrict__ wo,
    u16* __restrict__ wkTf, float* __restrict__ bkv,
    float* __restrict__ wvp, float* __restrict__ bvp) {
  const int t = threadIdx.x;
  if (blockIdx.x < 512) {
    const int gid = blockIdx.x * 256 + t;
    const int hm = gid & 255, e = gid >> 8;
    const int h = hm >> 4, m = hm & 15;
    float acc = 0.f;
    for (int d = 0; d < 128; d++)
      acc += wi[e * 2048 + h * 128 + d] * wm[d * 16 + m];
    wkTf[((((size_t)(e >> 3)) * 256 + hm) << 3) + (e & 7)] = f2bf(acc);
  } else if (blockIdx.x < 640) {
    __shared__ float wmv_l[16][16];
    __shared__ float bmv_l[16];
    const int blk = blockIdx.x - 512;
    const int h = blk >> 3, dc = blk & 7;
    {
      const int m = t >> 4, dd = t & 15;
      wmv_l[m][dd] = mv[m * 128 + dc * 16 + dd];
      if (t < 16) bmv_l[t] = b_mv[dc * 16 + t];
    }
    __syncthreads();
    float acc0[16], acc1[16];
    float bv0 = 0.f, bv1 = 0.f;
#pragma unroll
    for (int m = 0; m < 16; m++) { acc0[m] = 0.f; acc1[m] = 0.f; }
#pragma unroll
    for (int dd = 0; dd < 16; dd++) {
      const float w0 = wo[(size_t)(h * 128 + dc * 16 + dd) * 512 + t];
      const float w1 = wo[(size_t)(h * 128 + dc * 16 + dd) * 512 + 256 + t];
#pragma unroll
      for (int m = 0; m < 16; m++) {
        const float c = wmv_l[m][dd];
        acc0[m] += c * w0;
        acc1[m] += c * w1;
      }
      bv0 += bmv_l[dd] * w0;
      bv1 += bmv_l[dd] * w1;
    }
    float* w0p = wvp + ((size_t)blk * 512 + t) * 16;
    float* w1p = wvp + ((size_t)blk * 512 + 256 + t) * 16;
#pragma unroll
    for (int m = 0; m < 16; m++) { w0p[m] = acc0[m]; w1p[m] = acc1[m]; }
    bvp[(size_t)blk * 512 + t] = bv0;
    bvp[(size_t)blk * 512 + 256 + t] = bv1;
  } else {
    const int h = t >> 4, m = t & 15;
    float acc = b_mk[m];
    for (int d = 0; d < 128; d++) acc += b_in[h * 128 + d] * wm[d * 16 + m];
    bkv[t] = acc;
  }
}

// ---------------------------------------------------------------------------
// GEMM A + fused wvt_fin tail blocks.
// Blocks 0..1023: logits[32768,256] = x @ Wk + bk (bf16) + colsum partials.
//   (4 waves; wave = 32r x 64c, acc[2][4]; block = 32 rows x ALL 256 cols;
//    BK=64 A-dbuf via global_load_lds; B per-lane frags from wkTf.)
// Blocks 1024..1535: wvt_fin for e = blk-1024 (independent outputs).
__global__ __launch_bounds__(256, 2) void gemm_a(const float* __restrict__ x,
                                                 const u16* __restrict__ wkTf,
                                                 const float* __restrict__ bk,
                                                 u16* __restrict__ logits,
                                                 float* __restrict__ cpart,
                                                 const float* __restrict__ wvp,
                                                 const float* __restrict__ bvp,
                                                 const float* __restrict__ b_out,
                                                 u16* __restrict__ wvTf,
                                                 float* __restrict__ bv) {
  __shared__ float Asf[2][2048];  // 2 x 8 KB: 32 rows x 256 B (swizzled)
  const int t = threadIdx.x;

  if (blockIdx.x >= 1024) {
    // ---- fused wvt_fin: wvT_f[hm>>3][e][hm&7]; bv[e] ----
    const int e = blockIdx.x - 1024;  // 512
    const int h = t >> 4, m = t & 15;
    float s = 0.f;
#pragma unroll
    for (int dc = 0; dc < 8; dc++)
      s += wvp[((size_t)(h * 8 + dc) * 512 + e) * 16 + m];
    wvTf[((((size_t)(t >> 3)) * 512 + e) << 3) + (t & 7)] = f2bf(s);
    if (t < 64) {
      float b = bvp[(size_t)t * 512 + e] + bvp[(size_t)(t + 64) * 512 + e];
#pragma unroll
      for (int mask = 32; mask >= 1; mask >>= 1) b += __shfl_xor(b, mask);
      if (t == 0) bv[e] = b_out[e] + b;
    }
    return;
  }

  const int l = t & 63, w = t >> 6;
  const int lrow = l & 15, lkg = l >> 4;
  const int gRow0 = blockIdx.x << 5;

  const char* xb = (const char*)x;
  const char* gA[2]; int lAo[2];
#pragma unroll
  for (int p = 0; p < 2; p++) {
    const int o = p * 4096 + t * 16;              // phys byte 0..8191
    const int row = o >> 8, pin = o & 255;
    const int lin = pin ^ ((row & 7) << 5);       // logical byte in 256B row
    gA[p] = xb + (size_t)(gRow0 + row) * 2048 + lin;
    lAo[p] = o;
  }
  const int col0 = w * 64 + lrow;                 // + n*16

  f32x4 acc[2][4];
#pragma unroll
  for (int i = 0; i < 2; i++)
#pragma unroll
    for (int n = 0; n < 4; n++) acc[i][n] = f32x4{0.f, 0.f, 0.f, 0.f};

  uint4 bReg[2][4];
#pragma unroll
  for (int p = 0; p < 2; p++) gl16(gA[p], (char*)(&Asf[0][0]) + lAo[p]);
#pragma unroll
  for (int n = 0; n < 4; n++)
    bReg[0][n] = *(const uint4*)(wkTf + ((size_t)lkg * 256 + col0 + n * 16) * 8);
  __syncthreads();

  for (int kc = 0; kc < 8; ++kc) {
    const int buf = kc & 1;
    if (kc < 7) {
#pragma unroll
      for (int p = 0; p < 2; p++)
        gl16(gA[p] + (size_t)(kc + 1) * 256, (char*)(&Asf[buf ^ 1][0]) + lAo[p]);
    }
#pragma unroll
    for (int s = 0; s < 2; ++s) {
      const int nkc = (s == 0) ? kc : kc + 1;
      const int nss = s ^ 1;
      if (nkc < 8) {
#pragma unroll
        for (int n = 0; n < 4; n++)
          bReg[s ^ 1][n] = *(const uint4*)(
              wkTf + ((size_t)(nkc * 8 + nss * 4 + lkg) * 256 + col0 + n * 16) * 8);
      }
      s16x8 af[2];
#pragma unroll
      for (int i = 0; i < 2; i++) {
        const int r = i * 16 + lrow;
        const int phys = (s * 128 + lkg * 32) ^ ((r & 7) << 5);
        const float4 a0 = *(const float4*)&Asf[buf][r * 64 + (phys >> 2)];
        const float4 a1 = *(const float4*)&Asf[buf][r * 64 + (phys >> 2) + 4];
        af[i] = as_s16x8(pack_bf8(a0, a1));
      }
#pragma unroll
      for (int n = 0; n < 4; n++) {
        const s16x8 bfr = as_s16x8(bReg[s][n]);
#pragma unroll
        for (int i = 0; i < 2; i++) mfma_bf16(acc[i][n], af[i], bfr);
      }
    }
    __syncthreads();
  }

  asm volatile("s_nop 7\n\ts_nop 7");
  const int crow = lkg * 4;  // C/D: row = (l>>4)*4 + j, col = l&15
  float esum[4];
#pragma unroll
  for (int n = 0; n < 4; n++) {
    const int col = w * 64 + n * 16 + lrow;
    const float bias = bk[col];
    float es = 0.f;
#pragma unroll
    for (int i = 0; i < 2; i++) {
      const int row0 = gRow0 + i * 16 + crow;
#pragma unroll
      for (int j = 0; j < 4; j++) {
        const u16 q = f2bf(acc[i][n][j] + bias);
        logits[(size_t)(row0 + j) * 256 + col] = q;
        es += __expf(bf2f(q));
      }
    }
    esum[n] = es;
  }
#pragma unroll
  for (int n = 0; n < 4; n++) {
    esum[n] += __shfl_xor(esum[n], 16);
    esum[n] += __shfl_xor(esum[n], 32);
  }
  if (l < 16) {
#pragma unroll
    for (int n = 0; n < 4; n++)
      cpart[(size_t)blockIdx.x * 256 + w * 64 + n * 16 + l] = esum[n];
  }
}

// ---------------------------------------------------------------------------
// GEMM B: out[32768,512] = P @ Wv + bv (fp32 out). colsum_fin fused (32
// cpart chunks per batch). Structure unchanged from round 17.
__global__ __launch_bounds__(512, 2) void gemm_b(const u16* __restrict__ lg,
                                                 const float* __restrict__ cpart,
                                                 const u16* __restrict__ wvTf,
                                                 const float* __restrict__ bvv,
                                                 float* __restrict__ out) {
  __shared__ u16 Bsh[2][16384];  // 2 x 32 KB
  __shared__ float invl[256];
  const int t = threadIdx.x;
  const int l = t & 63, w = t >> 6;
  const int lrow = l & 15, lkg = l >> 4;
  const int rowg = w >> 1, ch = w & 1;
  const int gRow0 = blockIdx.x << 6;
  const int bIdx = blockIdx.x >> 4;   // 16 row-blocks (64r) per batch
  const int rowBase = gRow0 + rowg * 16;

  // fused colsum_fin: inv into LDS (batch = 32 cpart chunks of 32 rows)
  if (t < 256) {
    float s = 0.f;
#pragma unroll
    for (int k = 0; k < 32; k++) s += cpart[(size_t)(bIdx * 32 + k) * 256 + t];
    invl[t] = 1.0f / s;
  }
  __syncthreads();

  // issue stage(kc=0) early — overlaps with phase A's lg loads
#pragma unroll
  for (int i = 0; i < 4; ++i) {
    const int c = i * 512 + t;                 // cell: kgl = c>>9, e = c&511
    gl16(wvTf + (size_t)c * 8, (char*)(&Bsh[0][0]) + c * 16);
  }

  // ---- phase A: softmax -> af[8] in registers ----
  const u16* aBase = lg + (size_t)(rowBase + lrow) * 256 + lkg * 8;
  s16x8 af[8];
#pragma unroll
  for (int kc = 0; kc < 8; ++kc) {
    const uint4 q = *(const uint4*)(aBase + kc * 32);
    const float4 i0 = *(const float4*)&invl[kc * 32 + lkg * 8];
    const float4 i1 = *(const float4*)&invl[kc * 32 + lkg * 8 + 4];
    const float e0 = __expf(bf2f((u16)(q.x & 0xffffu))) * i0.x;
    const float e1 = __expf(bf2f((u16)(q.x >> 16)))     * i0.y;
    const float e2 = __expf(bf2f((u16)(q.y & 0xffffu))) * i0.z;
    const float e3 = __expf(bf2f((u16)(q.y >> 16)))     * i0.w;
    const float e4 = __expf(bf2f((u16)(q.z & 0xffffu))) * i1.x;
    const float e5 = __expf(bf2f((u16)(q.z >> 16)))     * i1.y;
    const float e6 = __expf(bf2f((u16)(q.w & 0xffffu))) * i1.z;
    const float e7 = __expf(bf2f((u16)(q.w >> 16)))     * i1.w;
    float s = ((e0 + e1) + (e2 + e3)) + ((e4 + e5) + (e6 + e7));
    s += __shfl_xor(s, 16);  // lkg 0<->1 (head 2kc), 2<->3 (head 2kc+1)
    const float rs = 1.0f / (s + 1e-9f);
    af[kc] = as_s16x8(make_uint4(cvt2(e0 * rs, e1 * rs), cvt2(e2 * rs, e3 * rs),
                                 cvt2(e4 * rs, e5 * rs), cvt2(e6 * rs, e7 * rs)));
  }
  __syncthreads();  // vmcnt(0): Bsh[0] staged; all waves past phase A

  f32x4 acc[16];
#pragma unroll
  for (int n = 0; n < 16; n++) acc[n] = f32x4{0.f, 0.f, 0.f, 0.f};

  for (int kc = 0; kc < 8; ++kc) {
    const int buf = kc & 1;
    if (kc < 7) {
#pragma unroll
      for (int i = 0; i < 4; ++i) {
        const int c = i * 512 + t;
        gl16(wvTf + ((size_t)(kc + 1) * 2048 + c) * 8,
             (char*)(&Bsh[buf ^ 1][0]) + c * 16);
      }
    }
#pragma unroll
    for (int n = 0; n < 16; ++n) {
      const s16x8 bfr = *(const s16x8*)
          &Bsh[buf][((lkg * 512 + ch * 256 + n * 16 + lrow)) * 8];
      mfma_bf16(acc[n], af[kc], bfr);
    }
    __syncthreads();  // vmcnt(0): next chunk staged; buf reads complete
  }

  asm volatile("s_nop 7\n\ts_nop 7");
#pragma unroll
  for (int n = 0; n < 16; ++n) {
    const int col = ch * 256 + n * 16 + lrow;
    const float bias = bvv[col];
#pragma unroll
    for (int j = 0; j < 4; ++j)
      out[(size_t)(rowBase + lkg * 4 + j) * 512 + col] = acc[n][j] + bias;
  }
}

// ---------------------------------------------------------------------------
extern "C" void kernel_launch(void* const* d_in, const int* in_sizes, int n_in,
                              void* d_out, int out_size, void* d_ws, size_t ws_size,
                              hipStream_t stream) {
  (void)in_sizes; (void)n_in; (void)out_size; (void)ws_size;
  const float* x     = (const float*)d_in[0];
  const float* W_in  = (const float*)d_in[1];
  const float* b_in  = (const float*)d_in[2];
  const float* W_mk  = (const float*)d_in[3];
  const float* b_mk  = (const float*)d_in[4];
  const float* W_mv  = (const float*)d_in[5];
  const float* b_mv  = (const float*)d_in[6];
  const float* W_out = (const float*)d_in[7];
  const float* b_out = (const float*)d_in[8];

  char* ws = (char*)d_ws;
  u16*   wkTf = (u16*)(ws + OFF_WKT);
  u16*   wvTf = (u16*)(ws + OFF_WVT);
  float* bk   = (float*)(ws + OFF_BK);
  float* bv   = (float*)(ws + OFF_BV);
  float* cp   = (float*)(ws + OFF_CP);
  u16*   lg   = (u16*)(ws + OFF_LOG);
  float* wvp  = (float*)(ws + OFF_WVP);
  float* bvp  = (float*)(ws + OFF_BVP);
  float* outp = (float*)d_out;

  prep_all<<<641, 256, 0, stream>>>(W_in, W_mk, b_in, b_mk, W_mv, b_mv, W_out,
                                    wkTf, bk, wvp, bvp);
  gemm_a<<<1536, 256, 0, stream>>>(x, wkTf, bk, lg, cp,
                                   wvp, bvp, b_out, wvTf, bv);
  gemm_b<<<512, 512, 0, stream>>>(lg, cp, wvTf, bv, outp);
}